// Round 7
// baseline (3468.560 us; speedup 1.0000x reference)
//
#include <hip/hip_runtime.h>
#include <stdint.h>
#include <math.h>

// ---------------------------------------------------------------------------
// RSNN forward, MI355X. EXACT integer hidden GEMM as rounds 3-5 (passed,
// absmax 0.0156): 27-bit fixed-point weights -> 3 signed base-256 i8 digit
// planes, binary activations, i32 MFMA, exact int64 recombination, single
// fp32 round, fp32 program-order decay.
// Round-7: ONE persistent kernel via plain launch (256 blocks = 1/CU
// guaranteed co-resident; static ~8KB LDS; no hipLaunchCooperativeKernel)
// with a custom sense-reversing device barrier (agent-scope atomics).
// Block = 32 h-cols x 64 batch rows; weights streamed from (XCD-pinned) L2;
// hidden membranes in VGPRs; spikes double-buffered in global; input for all
// 50 steps pre-staged; o-layer exact-double partials + per-step reduce.
// ---------------------------------------------------------------------------

#define B_   256
#define T_   50
#define I_   1024
#define H_   2048
#define O_   20

#define XIN_T  262144     // bytes per t: 4 bt * 16 kx * 4096
#define XS_BUF 524288     // one spike buffer: 4 bt * 32 kx * 4096

typedef __attribute__((ext_vector_type(4))) int intx4;
typedef long long ll_t;

// ---------------------------------------------------------------------------
// Weight prep: digit p of W(n, kk) -> image [ct16 128][p 3][kx 48][row16*64B]
// ---------------------------------------------------------------------------
__device__ __forceinline__ int digit_of(float v, int p) {
  int W = (int)rintf(v * 134217728.0f);   // exact: |W| <= 2^22
  int c0 = ((W + 128) & 255) - 128;
  int W1 = (W - c0) >> 8;
  int c1 = ((W1 + 128) & 255) - 128;
  int W2 = (W1 - c1) >> 8;
  return (p == 0) ? c0 : (p == 1) ? c1 : W2;
}

__global__ void prep_w(const float* __restrict__ w_ih,
                       const float* __restrict__ w_hh,
                       int8_t* __restrict__ Wtl) {
  int blk = blockIdx.x;
  int n = blk / 9, kg = blk % 9;
  int k9 = (kg * 256 + (int)threadIdx.x) * 4;   // [0, 9216)
  int p = k9 / 3072, kk = k9 % 3072;
  const float* src = (kk < 1024) ? (w_ih + n * I_ + kk)
                                 : (w_hh + n * H_ + (kk - 1024));
  float4 v = *(const float4*)src;
  int d0 = digit_of(v.x, p) & 255;
  int d1 = digit_of(v.y, p) & 255;
  int d2 = digit_of(v.z, p) & 255;
  int d3 = digit_of(v.w, p) & 255;
  int packed = d0 | (d1 << 8) | (d2 << 16) | (d3 << 24);
  int ct16 = n >> 4, row = n & 15;
  size_t off = (size_t)ct16 * 147456 + (size_t)p * 49152 + (kk >> 6) * 1024 +
               row * 64 + (kk & 63);
  *(int*)(Wtl + off) = packed;
}

// ---------------------------------------------------------------------------
// Init: pack input for ALL t, zero spike buf0, WhoD double, alphaH, barrier.
// grid 256 x 256 (65536 threads).
// ---------------------------------------------------------------------------
__global__ void init_k(int8_t* __restrict__ Xin, int8_t* __restrict__ Xs,
                       const float* __restrict__ input,
                       const float* __restrict__ tau_h, float* __restrict__ AlphaH,
                       const float* __restrict__ w_ho, double* __restrict__ WhoD,
                       unsigned* __restrict__ Bar) {
  int id = blockIdx.x * 256 + threadIdx.x;   // [0, 65536)
  {
    int b = id >> 8, i4 = (id & 255) * 4;
    for (int t = 0; t < T_; ++t) {
      float4 v = *(const float4*)(input + ((size_t)(b * T_ + t) << 10) + i4);
      uchar4 pk;
      pk.x = v.x > 0.5f ? 1 : 0;
      pk.y = v.y > 0.5f ? 1 : 0;
      pk.z = v.z > 0.5f ? 1 : 0;
      pk.w = v.w > 0.5f ? 1 : 0;
      *(uchar4*)(Xin + (size_t)t * XIN_T + (b >> 6) * 65536 + (i4 >> 6) * 4096 +
                 (b & 63) * 64 + (i4 & 63)) = pk;
    }
  }
  *(double*)(Xs + (size_t)id * 8) = 0.0;   // zero buf0 (524288 B)
  if (id < 64 * O_ * 32) {                 // WhoD [ct32 64][o 20][hl 32]
    int ct = id / 640, rem = id % 640, o = rem / 32, hl = rem & 31;
    WhoD[id] = (double)w_ho[o * H_ + ct * 32 + hl];
  }
  if (id < H_) AlphaH[id] = (float)exp((double)(-1.0f / tau_h[id]));
  if (id == 0) { Bar[0] = 0u; Bar[1] = 0u; }
}

// ---------------------------------------------------------------------------
// Persistent kernel: 256 blocks x 256 threads (1 block/CU).
// Block (ct in [0,64), rg in [0,4)): 32 h-cols x 64 batch rows, full K.
// ---------------------------------------------------------------------------
__global__ __launch_bounds__(256, 1) void rsnn_pers(
    const int8_t* __restrict__ Wtl, const int8_t* __restrict__ Xin,
    int8_t* __restrict__ Xs, double* __restrict__ Po,
    const double* __restrict__ WhoD, const float* __restrict__ AlphaH,
    const float* __restrict__ tau_o, unsigned* __restrict__ Bar,
    float* __restrict__ out) {
  __shared__ double WhoL[640];
  __shared__ int8_t spk_l[2048];
  __shared__ double rsum[O_];
  __shared__ float om_l[O_];

  const int j = blockIdx.x;
  const int ct = (j & 7) * 8 + (j >> 5);   // XCD-grouped: same j%8 -> same cts
  const int rg = (j >> 3) & 3;
  const int tid = threadIdx.x;
  const int l = tid & 63, wv = tid >> 6;
  const int wm = wv >> 1, wn = wv & 1;
  const int r_ = l & 15, q = l >> 4;
  const int ct16 = ct * 2 + wn;
  const int h = ct16 * 16 + r_;

  for (int i = tid; i < 640; i += 256) WhoL[i] = WhoD[ct * 640 + i];
  const float alpha_lane = AlphaH[h];
  float alphaO_r = 0.f;
  if (tid < O_) alphaO_r = (float)exp((double)(-1.0f / tau_o[tid]));
  float Om_r = 0.f, Osu_r = 0.f, Mo_r = 0.f;
  float hm_r[2][4] = {{0.f, 0.f, 0.f, 0.f}, {0.f, 0.f, 0.f, 0.f}};
  __syncthreads();

  const int arow = (wm * 32 + r_) * 64 + q * 16;
  const int8_t* Bb = Wtl + (size_t)ct16 * 147456 + r_ * 64 + q * 16;

  for (int t = 0; t < T_; ++t) {
    const int8_t* Ain = Xin + (size_t)t * XIN_T + rg * 65536 + arow;
    const int8_t* Asp = Xs + (size_t)(t & 1) * XS_BUF + rg * 131072 + arow;

    intx4 acc[2][3];
#pragma unroll
    for (int f = 0; f < 2; ++f)
#pragma unroll
      for (int p = 0; p < 3; ++p) acc[f][p] = (intx4){0, 0, 0, 0};

    intx4 ap[4][2], bp[4][3];
#pragma unroll
    for (int u = 0; u < 4; ++u) {
      ap[u][0] = *(const intx4*)(Ain + u * 4096);
      ap[u][1] = *(const intx4*)(Ain + u * 4096 + 1024);
#pragma unroll
      for (int p = 0; p < 3; ++p)
        bp[u][p] = *(const intx4*)(Bb + p * 49152 + u * 1024);
    }
#pragma unroll 4
    for (int u = 0; u < 48; ++u) {
      const int s = u & 3;
      intx4 a0 = ap[s][0], a1 = ap[s][1];
#pragma unroll
      for (int p = 0; p < 3; ++p) {
        acc[0][p] = __builtin_amdgcn_mfma_i32_16x16x64_i8(a0, bp[s][p], acc[0][p], 0, 0, 0);
        acc[1][p] = __builtin_amdgcn_mfma_i32_16x16x64_i8(a1, bp[s][p], acc[1][p], 0, 0, 0);
      }
      const int un = u + 4;
      if (un < 48) {
        const int8_t* a = (un < 16) ? (Ain + un * 4096) : (Asp + (un - 16) * 4096);
        ap[s][0] = *(const intx4*)a;
        ap[s][1] = *(const intx4*)(a + 1024);
#pragma unroll
        for (int p = 0; p < 3; ++p)
          bp[s][p] = *(const intx4*)(Bb + p * 49152 + un * 1024);
      }
    }

    // hidden epilogue: exact recombine, single fp32 round, decay, spike
    int8_t* Xw = Xs + (size_t)((t + 1) & 1) * XS_BUF + rg * 131072 +
                 (h >> 6) * 4096 + (h & 63);
#pragma unroll
    for (int f = 0; f < 2; ++f)
#pragma unroll
      for (int jj = 0; jj < 4; ++jj) {
        ll_t S = (ll_t)acc[f][0][jj] + ((ll_t)acc[f][1][jj] << 8) +
                 ((ll_t)acc[f][2][jj] << 16);
        float M = (float)((double)S * 7.450580596923828125e-9);  // * 2^-27
        float hp = hm_r[f][jj];
        float spf = (hp - 0.3f) > 0.f ? 1.f : 0.f;
        float hm = M + hp * alpha_lane * (1.0f - spf);
        hm_r[f][jj] = hm;
        int8_t spk = (hm - 0.3f) > 0.f ? 1 : 0;
        int row64 = wm * 32 + f * 16 + q * 4 + jj;
        spk_l[row64 * 32 + wn * 16 + r_] = spk;
        Xw[row64 * 64] = spk;
      }
    __syncthreads();

    // o-partials: thread (bl=tid>>2, 5 o's) dot over this block's 32 h-cols
    {
      int bl = tid >> 2, og = (tid & 3) * 5;
      const double* W0 = WhoL + og * 32;
      double a0 = 0, a1 = 0, a2 = 0, a3 = 0, a4 = 0;
#pragma unroll
      for (int hl = 0; hl < 32; ++hl) {
        double m = spk_l[bl * 32 + hl] ? 1.0 : 0.0;
        a0 += m * W0[hl];
        a1 += m * W0[32 + hl];
        a2 += m * W0[64 + hl];
        a3 += m * W0[96 + hl];
        a4 += m * W0[128 + hl];
      }
      // Po layout [slot 2][b 256][ct 64][o 20]
      double* dst = Po + (((size_t)(t & 1) * 256 + rg * 64 + bl) * 64 + ct) * 20 + og;
      dst[0] = a0; dst[1] = a1; dst[2] = a2; dst[3] = a3; dst[4] = a4;
    }
    __syncthreads();

    // ---- device barrier (sense-reversing, agent scope) ----
    if (tid == 0) {
      __threadfence();
      unsigned g = __hip_atomic_load(&Bar[1], __ATOMIC_RELAXED, __HIP_MEMORY_SCOPE_AGENT);
      unsigned a = __hip_atomic_fetch_add(&Bar[0], 1u, __ATOMIC_ACQ_REL, __HIP_MEMORY_SCOPE_AGENT);
      if (a == (unsigned)(gridDim.x - 1)) {
        __hip_atomic_store(&Bar[0], 0u, __ATOMIC_RELAXED, __HIP_MEMORY_SCOPE_AGENT);
        __hip_atomic_store(&Bar[1], g + 1u, __ATOMIC_RELEASE, __HIP_MEMORY_SCOPE_AGENT);
      } else {
        while (__hip_atomic_load(&Bar[1], __ATOMIC_ACQUIRE, __HIP_MEMORY_SCOPE_AGENT) == g)
          __builtin_amdgcn_s_sleep(2);
      }
      __threadfence();
    }
    __syncthreads();

    // ---- o-phase: block j = batch j; reduce 64 ct-partials, advance state
    {
      const double* pp = Po + (((size_t)(t & 1) * 256 + j) * 64 + l) * 20 + wv * 5;
      double v0 = pp[0], v1 = pp[1], v2 = pp[2], v3 = pp[3], v4 = pp[4];
#pragma unroll
      for (int mk = 32; mk >= 1; mk >>= 1) {
        v0 += __shfl_xor(v0, mk);
        v1 += __shfl_xor(v1, mk);
        v2 += __shfl_xor(v2, mk);
        v3 += __shfl_xor(v3, mk);
        v4 += __shfl_xor(v4, mk);
      }
      if (l == 0) {
        rsum[wv * 5 + 0] = v0; rsum[wv * 5 + 1] = v1; rsum[wv * 5 + 2] = v2;
        rsum[wv * 5 + 3] = v3; rsum[wv * 5 + 4] = v4;
      }
    }
    __syncthreads();
    if (tid < O_) {
      float r = (float)rsum[tid];   // single fp32 rounding of the double dot
      float spo = (Om_r - 0.3f) > 0.f ? 1.f : 0.f;
      float m = Om_r * alphaO_r * (1.0f - spo) + r;
      om_l[tid] = m;
      float mx = om_l[0];
#pragma unroll
      for (int o = 1; o < O_; ++o) mx = fmaxf(mx, om_l[o]);
      float se = 0.f;
#pragma unroll
      for (int o = 0; o < O_; ++o) se += expf(om_l[o] - mx);
      float sp = (m - 0.3f) > 0.f ? 1.f : 0.f;
      Om_r = m;
      Osu_r += sp;
      Mo_r += expf(m - mx) / se;
      if (t == T_ - 1) {
        out[j * O_ + tid] = Osu_r / 50.0f;
        out[B_ * O_ + j * O_ + tid] = Mo_r;
      }
    }
    __syncthreads();
  }
}

// ---------------------------------------------------------------------------
extern "C" void kernel_launch(void* const* d_in, const int* in_sizes, int n_in,
                              void* d_out, int out_size, void* d_ws, size_t ws_size,
                              hipStream_t stream) {
  const float* input = (const float*)d_in[0];
  const float* w_ih  = (const float*)d_in[1];
  const float* w_hh  = (const float*)d_in[2];
  const float* w_ho  = (const float*)d_in[3];
  const float* tau_h = (const float*)d_in[4];
  const float* tau_o = (const float*)d_in[5];

  char* ws = (char*)d_ws;
  // layout (bytes):
  // Wtl    @ 0          18,874,368
  // Xin    @ 18874368   13,107,200
  // Xs     @ 31981568    1,048,576
  // Po     @ 33030144    5,242,880
  // WhoD   @ 38273024      327,680
  // AlphaH @ 38600704        8,192
  // Bar    @ 38608896            8
  int8_t*   Wtl    = (int8_t*)(ws);
  int8_t*   Xin    = (int8_t*)(ws + 18874368);
  int8_t*   Xs     = (int8_t*)(ws + 31981568);
  double*   Po     = (double*)(ws + 33030144);
  double*   WhoD   = (double*)(ws + 38273024);
  float*    AlphaH = (float*)(ws + 38600704);
  unsigned* Bar    = (unsigned*)(ws + 38608896);
  float*    out    = (float*)d_out;

  prep_w<<<2048 * 9, 256, 0, stream>>>(w_ih, w_hh, Wtl);
  init_k<<<256, 256, 0, stream>>>(Xin, Xs, input, tau_h, AlphaH, w_ho, WhoD, Bar);
  rsnn_pers<<<256, 256, 0, stream>>>(Wtl, Xin, Xs, Po, WhoD, AlphaH, tau_o, Bar, out);
}

// Round 8
// 1665.245 us; speedup vs baseline: 2.0829x; 2.0829x over previous
//
#include <hip/hip_runtime.h>
#include <stdint.h>
#include <math.h>

// ---------------------------------------------------------------------------
// RSNN forward, MI355X. EXACT integer hidden GEMM (rounds 3-7, absmax
// 0.0156): 27-bit fixed-point weights -> 3 signed base-256 i8 digit planes,
// binary activations, i32 MFMA, exact int64 recombination, single fp32
// round, fp32 program-order decay.
// Round-8: one fused kernel per step (kernel boundary = the global sync; no
// device fences). Block = 32 batch x 64 h cols, FULL K, all 3 planes ->
// no partial-sum round-trip; Hm in-place; spikes double-buffered. Waves
// split (col-half c x K-half k): 12 accs/wave, depth-1 slab prefetch, zero
// K-loop barriers; 24 KB LDS exchange merges K-halves. Output layer:
// per-block 64-h double partials -> Po, reduced in next step's head.
// ---------------------------------------------------------------------------

#define B_   256
#define T_   50
#define I_   1024
#define H_   2048
#define O_   20
#define XIN_T  262144    // input bytes per t: 4 bt * 16 kx * 4096
#define XS_BUF 524288    // one spike buffer: 4 bt * 32 kx * 4096
#define WNT 589824       // weight bytes per nt: 3 planes * 48 slabs * 4096
#define WPL 196608       // bytes per plane within an nt

typedef __attribute__((ext_vector_type(4))) int intx4;
typedef long long ll_t;

// ---------------------------------------------------------------------------
// Weight prep: digit p of W(n,kk) -> [nt 32][p 3][kx 48][row64 * 64B]
// ---------------------------------------------------------------------------
__device__ __forceinline__ int digit_of(float v, int p) {
  int W = (int)rintf(v * 134217728.0f);   // exact: |W| <= 2^22
  int c0 = ((W + 128) & 255) - 128;
  int W1 = (W - c0) >> 8;
  int c1 = ((W1 + 128) & 255) - 128;
  int W2 = (W1 - c1) >> 8;
  return (p == 0) ? c0 : (p == 1) ? c1 : W2;
}

__global__ void prep_w(const float* __restrict__ w_ih,
                       const float* __restrict__ w_hh,
                       int8_t* __restrict__ Wtl) {
  int blk = blockIdx.x;
  int n = blk / 9, kg = blk % 9;
  int k9 = (kg * 256 + (int)threadIdx.x) * 4;   // [0, 9216)
  int p = k9 / 3072, kk = k9 % 3072;
  const float* src = (kk < 1024) ? (w_ih + n * I_ + kk)
                                 : (w_hh + n * H_ + (kk - 1024));
  float4 v = *(const float4*)src;
  int d0 = digit_of(v.x, p) & 255;
  int d1 = digit_of(v.y, p) & 255;
  int d2 = digit_of(v.z, p) & 255;
  int d3 = digit_of(v.w, p) & 255;
  int packed = d0 | (d1 << 8) | (d2 << 16) | (d3 << 24);
  size_t off = (size_t)(n >> 6) * WNT + (size_t)p * WPL + (kk >> 6) * 4096 +
               (n & 63) * 64 + (kk & 63);
  *(int*)(Wtl + off) = packed;
}

// ---------------------------------------------------------------------------
// Init: pack input for ALL t, zero spike buf0 + Hm + o-state, tables.
// grid 256 x 256 = 65536 threads.
// ---------------------------------------------------------------------------
__global__ void init_k(int8_t* __restrict__ Xin, int8_t* __restrict__ Xs,
                       float* __restrict__ Hm, const float* __restrict__ input,
                       const float* __restrict__ tau_h,
                       const float* __restrict__ tau_o,
                       float* __restrict__ AlphaH, float* __restrict__ AlphaO,
                       const float* __restrict__ w_ho, double* __restrict__ WhoD,
                       float* __restrict__ Om, float* __restrict__ Osp,
                       float* __restrict__ Osu, float* __restrict__ Mo) {
  int id = blockIdx.x * 256 + threadIdx.x;   // [0, 65536)
  {
    int b = id >> 8, i4 = (id & 255) * 4;
    for (int t = 0; t < T_; ++t) {
      float4 v = *(const float4*)(input + ((size_t)(b * T_ + t) << 10) + i4);
      uchar4 pk;
      pk.x = v.x > 0.5f ? 1 : 0;
      pk.y = v.y > 0.5f ? 1 : 0;
      pk.z = v.z > 0.5f ? 1 : 0;
      pk.w = v.w > 0.5f ? 1 : 0;
      *(uchar4*)(Xin + (size_t)t * XIN_T + (b >> 6) * 65536 + (i4 >> 6) * 4096 +
                 (b & 63) * 64 + (i4 & 63)) = pk;
    }
  }
  *(double*)(Xs + (size_t)id * 8) = 0.0;        // zero spike buf0
  *(float4*)(Hm + (size_t)id * 8) = make_float4(0.f, 0.f, 0.f, 0.f);
  *(float4*)(Hm + (size_t)id * 8 + 4) = make_float4(0.f, 0.f, 0.f, 0.f);
  if (id < 32 * O_ * 64) {                      // WhoD [nt 32][o 20][hl 64]
    int nt = id / 1280, rem = id % 1280, o = rem / 64, hl = rem & 63;
    WhoD[id] = (double)w_ho[o * H_ + nt * 64 + hl];
  }
  if (id < H_) AlphaH[id] = (float)exp((double)(-1.0f / tau_h[id]));
  if (id < O_) AlphaO[id] = (float)exp((double)(-1.0f / tau_o[id]));
  if (id < B_ * O_) {
    Om[id] = 0.f; Osp[id] = 0.f; Osu[id] = 0.f; Mo[id] = 0.f;
  }
}

// ---------------------------------------------------------------------------
// Per-step kernel: 256 blocks x 256 threads (1/CU). Block (nt, mt):
// 32 batch rows x 64 h cols, full K=3072, 3 planes. Waves: c=col-half,
// k=K-half (24 slabs each).
// ---------------------------------------------------------------------------
__global__ __launch_bounds__(256, 1) void step_k(
    const int8_t* __restrict__ Wtl, const int8_t* __restrict__ Xin,
    int8_t* __restrict__ Xs, float* __restrict__ Hm, double* __restrict__ Po,
    const double* __restrict__ WhoD, const float* __restrict__ AlphaH,
    const float* __restrict__ AlphaO, float* __restrict__ Om,
    float* __restrict__ Osp, float* __restrict__ Osu, float* __restrict__ Mo,
    int t) {
  __shared__ double WhoL[1280];
  __shared__ __align__(16) int8_t red[24576];
  __shared__ int8_t spk_lT[2048];   // [col 64][row 32]
  __shared__ float om_l[O_];

  const int j = blockIdx.x;
  const int nt = (j & 7) * 4 + (j >> 6);   // XCD-grouped weight panels
  const int mt = (j >> 3) & 7;
  const int tid = threadIdx.x;
  const int l = tid & 63, wv = tid >> 6;
  const int c = wv >> 1, k = wv & 1;
  const int r_ = l & 15, q = l >> 4;

  for (int i = tid; i < 1280; i += 256) WhoL[i] = WhoD[nt * 1280 + i];

  // ---- head: o-phase for step t-1 (block j = batch j) ----
  if (t > 0 && tid < O_) {
    const double* pp = Po + ((size_t)(((t - 1) & 1) * 256 + j) * 32) * 20 + tid;
    double s = 0.0;
#pragma unroll
    for (int n2 = 0; n2 < 32; ++n2) s += pp[n2 * 20];
    float r = (float)s;   // single fp32 rounding of exact-ish double dot
    float m = Om[j * O_ + tid] * AlphaO[tid] * (1.0f - Osp[j * O_ + tid]) + r;
    om_l[tid] = m;
  }
  __syncthreads();
  if (t > 0 && tid < O_) {
    float m = om_l[tid];
    float mx = om_l[0];
#pragma unroll
    for (int o = 1; o < O_; ++o) mx = fmaxf(mx, om_l[o]);
    float se = 0.f;
#pragma unroll
    for (int o = 0; o < O_; ++o) se += expf(om_l[o] - mx);
    float sp = (m - 0.3f) > 0.f ? 1.f : 0.f;
    Om[j * O_ + tid] = m;
    Osp[j * O_ + tid] = sp;
    Osu[j * O_ + tid] += sp;
    Mo[j * O_ + tid] += expf(m - mx) / se;
  }

  // ---- K-loop (no barriers) ----
  const int arow = ((mt & 1) * 32 + r_) * 64 + q * 16;
  const int8_t* Ain = Xin + (size_t)t * XIN_T + (mt >> 1) * 65536 + arow;
  const int8_t* Asp = Xs + (size_t)(t & 1) * XS_BUF + (mt >> 1) * 131072 + arow;
  const int8_t* Bw = Wtl + (size_t)nt * WNT + (c * 32 + r_) * 64 + q * 16;

  intx4 acc[2][2][3];   // [fr][fc][p]
#pragma unroll
  for (int fr = 0; fr < 2; ++fr)
#pragma unroll
    for (int fc = 0; fc < 2; ++fc)
#pragma unroll
      for (int p = 0; p < 3; ++p) acc[fr][fc][p] = (intx4){0, 0, 0, 0};

  const int u0 = k * 24;
  intx4 a[2][2], b[2][2][3];
  {
    const int8_t* ap = (u0 < 16) ? (Ain + u0 * 4096) : (Asp + (u0 - 16) * 4096);
    a[0][0] = *(const intx4*)ap;
    a[0][1] = *(const intx4*)(ap + 1024);
    const int8_t* bp = Bw + u0 * 4096;
#pragma unroll
    for (int p = 0; p < 3; ++p)
#pragma unroll
      for (int fc = 0; fc < 2; ++fc)
        b[0][fc][p] = *(const intx4*)(bp + p * WPL + fc * 1024);
  }
#pragma unroll
  for (int i = 0; i < 24; ++i) {
    const int cur = i & 1, nxt = cur ^ 1;
    if (i < 23) {
      const int un = u0 + i + 1;
      const int8_t* ap = (un < 16) ? (Ain + un * 4096) : (Asp + (un - 16) * 4096);
      a[nxt][0] = *(const intx4*)ap;
      a[nxt][1] = *(const intx4*)(ap + 1024);
      const int8_t* bp = Bw + un * 4096;
#pragma unroll
      for (int p = 0; p < 3; ++p)
#pragma unroll
        for (int fc = 0; fc < 2; ++fc)
          b[nxt][fc][p] = *(const intx4*)(bp + p * WPL + fc * 1024);
    }
#pragma unroll
    for (int p = 0; p < 3; ++p)
#pragma unroll
      for (int fc = 0; fc < 2; ++fc) {
        acc[0][fc][p] = __builtin_amdgcn_mfma_i32_16x16x64_i8(
            a[cur][0], b[cur][fc][p], acc[0][fc][p], 0, 0, 0);
        acc[1][fc][p] = __builtin_amdgcn_mfma_i32_16x16x64_i8(
            a[cur][1], b[cur][fc][p], acc[1][fc][p], 0, 0, 0);
      }
  }

  // ---- merge K-halves via LDS: wave (c,k) owns fr=k ----
  {
    const int slot = c * 2 + (k ^ 1);
#pragma unroll
    for (int fc = 0; fc < 2; ++fc)
#pragma unroll
      for (int p = 0; p < 3; ++p)
        *(intx4*)(red + ((slot * 6 + fc * 3 + p) * 64 + l) * 16) =
            acc[k ^ 1][fc][p];
  }
  __syncthreads();
  intx4 S[2][3];
  {
    const int slot = c * 2 + k;
#pragma unroll
    for (int fc = 0; fc < 2; ++fc)
#pragma unroll
      for (int p = 0; p < 3; ++p)
        S[fc][p] = acc[k][fc][p] +
                   *(const intx4*)(red + ((slot * 6 + fc * 3 + p) * 64 + l) * 16);
  }

  // ---- hidden epilogue: exact recombine, fp32 round, decay, spike ----
  int8_t* Xw = Xs + (size_t)((t + 1) & 1) * XS_BUF;
  const int h0 = nt * 64 + c * 32 + r_;
#pragma unroll
  for (int fc = 0; fc < 2; ++fc) {
    const int h = h0 + fc * 16;
    const float alpha = AlphaH[h];
    unsigned spkpack = 0;
#pragma unroll
    for (int jj = 0; jj < 4; ++jj) {
      ll_t Sv = (ll_t)S[fc][0][jj] + ((ll_t)S[fc][1][jj] << 8) +
                ((ll_t)S[fc][2][jj] << 16);
      float M = (float)((double)Sv * 7.450580596923828125e-9);   // * 2^-27
      const int brow = mt * 32 + k * 16 + q * 4 + jj;
      const int idx = brow * H_ + h;
      float hp = Hm[idx];
      float spf = (hp - 0.3f) > 0.f ? 1.f : 0.f;
      float hm = M + hp * alpha * (1.0f - spf);   // fp32 program order
      Hm[idx] = hm;
      unsigned spk = (hm - 0.3f) > 0.f ? 1u : 0u;
      Xw[(brow >> 6) * 131072 + (h >> 6) * 4096 + (brow & 63) * 64 + (h & 63)] =
          (int8_t)spk;
      spkpack |= spk << (8 * jj);
    }
    *(unsigned*)(spk_lT + (c * 32 + fc * 16 + r_) * 32 + k * 16 + q * 4) =
        spkpack;
  }
  __syncthreads();

  // ---- o-partials: 64-h double dot, Po[t&1][b][nt][o] ----
  if (tid < 128) {
    const int bl = tid >> 2, og = (tid & 3) * 5;
    const double* W0 = WhoL + og * 64;
    double a0 = 0, a1 = 0, a2 = 0, a3 = 0, a4 = 0;
#pragma unroll
    for (int hl = 0; hl < 64; ++hl) {
      double m = (double)spk_lT[hl * 32 + bl];
      a0 += m * W0[hl];
      a1 += m * W0[64 + hl];
      a2 += m * W0[128 + hl];
      a3 += m * W0[192 + hl];
      a4 += m * W0[256 + hl];
    }
    double* dst =
        Po + ((size_t)((t & 1) * 256 + mt * 32 + bl) * 32 + nt) * 20 + og;
    dst[0] = a0; dst[1] = a1; dst[2] = a2; dst[3] = a3; dst[4] = a4;
  }
}

// ---------------------------------------------------------------------------
// Final o-phase (t=49) + output write. 256 blocks x 64 threads.
// ---------------------------------------------------------------------------
__global__ void final_k(const double* __restrict__ Po,
                        const float* __restrict__ AlphaO,
                        const float* __restrict__ Om,
                        const float* __restrict__ Osp,
                        const float* __restrict__ Osu,
                        const float* __restrict__ Mo, float* __restrict__ out) {
  __shared__ float om_l[O_];
  const int j = blockIdx.x, tid = threadIdx.x;
  if (tid < O_) {
    const double* pp = Po + ((size_t)(256 + j) * 32) * 20 + tid;   // slot 1
    double s = 0.0;
#pragma unroll
    for (int n2 = 0; n2 < 32; ++n2) s += pp[n2 * 20];
    float r = (float)s;
    float m = Om[j * O_ + tid] * AlphaO[tid] * (1.0f - Osp[j * O_ + tid]) + r;
    om_l[tid] = m;
  }
  __syncthreads();
  if (tid < O_) {
    float m = om_l[tid];
    float mx = om_l[0];
#pragma unroll
    for (int o = 1; o < O_; ++o) mx = fmaxf(mx, om_l[o]);
    float se = 0.f;
#pragma unroll
    for (int o = 0; o < O_; ++o) se += expf(om_l[o] - mx);
    float sp = (m - 0.3f) > 0.f ? 1.f : 0.f;
    out[j * O_ + tid] = (Osu[j * O_ + tid] + sp) / 50.0f;
    out[B_ * O_ + j * O_ + tid] = Mo[j * O_ + tid] + expf(m - mx) / se;
  }
}

// ---------------------------------------------------------------------------
extern "C" void kernel_launch(void* const* d_in, const int* in_sizes, int n_in,
                              void* d_out, int out_size, void* d_ws, size_t ws_size,
                              hipStream_t stream) {
  const float* input = (const float*)d_in[0];
  const float* w_ih  = (const float*)d_in[1];
  const float* w_hh  = (const float*)d_in[2];
  const float* w_ho  = (const float*)d_in[3];
  const float* tau_h = (const float*)d_in[4];
  const float* tau_o = (const float*)d_in[5];

  char* ws = (char*)d_ws;
  // layout (bytes):
  // Wtl    @ 0          18,874,368
  // Xin    @ 18874368   13,107,200
  // Xs     @ 31981568    1,048,576
  // Po     @ 33030144    2,621,440
  // Hm     @ 35651584    2,097,152
  // WhoD   @ 37748736      327,680
  // AlphaH @ 38076416        8,192
  // AlphaO @ 38084608          128
  // Om     @ 38084736       20,480  (then Osp, Osu, Mo)
  int8_t* Wtl    = (int8_t*)(ws);
  int8_t* Xin    = (int8_t*)(ws + 18874368);
  int8_t* Xs     = (int8_t*)(ws + 31981568);
  double* Po     = (double*)(ws + 33030144);
  float*  Hm     = (float*)(ws + 35651584);
  double* WhoD   = (double*)(ws + 37748736);
  float*  AlphaH = (float*)(ws + 38076416);
  float*  AlphaO = (float*)(ws + 38084608);
  float*  Om     = (float*)(ws + 38084736);
  float*  Osp    = (float*)(ws + 38105216);
  float*  Osu    = (float*)(ws + 38125696);
  float*  Mo     = (float*)(ws + 38146176);
  float*  out    = (float*)d_out;

  prep_w<<<2048 * 9, 256, 0, stream>>>(w_ih, w_hh, Wtl);
  init_k<<<256, 256, 0, stream>>>(Xin, Xs, Hm, input, tau_h, tau_o, AlphaH,
                                  AlphaO, w_ho, WhoD, Om, Osp, Osu, Mo);
  for (int t = 0; t < T_; ++t) {
    step_k<<<256, 256, 0, stream>>>(Wtl, Xin, Xs, Hm, Po, WhoD, AlphaH, AlphaO,
                                    Om, Osp, Osu, Mo, t);
  }
  final_k<<<256, 64, 0, stream>>>(Po, AlphaO, Om, Osp, Osu, Mo, out);
}

// Round 9
// 1109.904 us; speedup vs baseline: 3.1251x; 1.5004x over previous
//
#include <hip/hip_runtime.h>
#include <stdint.h>
#include <math.h>

// ---------------------------------------------------------------------------
// RSNN forward, MI355X. EXACT integer hidden GEMM (rounds 3-8, absmax
// 0.0156): 27-bit fixed-point weights -> 3 signed base-256 i8 digit planes,
// binary activations, i32 MFMA, exact int64 recombination, single fp32
// round, fp32 program-order decay.
// Round-9: occupancy fix. Same fused per-step kernel and block geometry
// (32 batch x 64 h, full K, no partial round-trip), but 512 threads =
// 8 waves = 2 waves/SIMD (was 1 -> zero TLP, latency-serialized). K splits
// 4-ways per wave (12 slabs); exact i32 LDS pairwise merge (2 barriers).
// ---------------------------------------------------------------------------

#define B_   256
#define T_   50
#define I_   1024
#define H_   2048
#define O_   20
#define XIN_T  262144    // input bytes per t: 4 bt * 16 kx * 4096
#define XS_BUF 524288    // one spike buffer: 4 bt * 32 kx * 4096
#define WNT 589824       // weight bytes per nt: 3 planes * 48 slabs * 4096
#define WPL 196608       // bytes per plane within an nt

typedef __attribute__((ext_vector_type(4))) int intx4;
typedef long long ll_t;

// ---------------------------------------------------------------------------
// Weight prep: digit p of W(n,kk) -> [nt 32][p 3][kx 48][row64 * 64B]
// ---------------------------------------------------------------------------
__device__ __forceinline__ int digit_of(float v, int p) {
  int W = (int)rintf(v * 134217728.0f);   // exact: |W| <= 2^22
  int c0 = ((W + 128) & 255) - 128;
  int W1 = (W - c0) >> 8;
  int c1 = ((W1 + 128) & 255) - 128;
  int W2 = (W1 - c1) >> 8;
  return (p == 0) ? c0 : (p == 1) ? c1 : W2;
}

__global__ void prep_w(const float* __restrict__ w_ih,
                       const float* __restrict__ w_hh,
                       int8_t* __restrict__ Wtl) {
  int blk = blockIdx.x;
  int n = blk / 9, kg = blk % 9;
  int k9 = (kg * 256 + (int)threadIdx.x) * 4;   // [0, 9216)
  int p = k9 / 3072, kk = k9 % 3072;
  const float* src = (kk < 1024) ? (w_ih + n * I_ + kk)
                                 : (w_hh + n * H_ + (kk - 1024));
  float4 v = *(const float4*)src;
  int d0 = digit_of(v.x, p) & 255;
  int d1 = digit_of(v.y, p) & 255;
  int d2 = digit_of(v.z, p) & 255;
  int d3 = digit_of(v.w, p) & 255;
  int packed = d0 | (d1 << 8) | (d2 << 16) | (d3 << 24);
  size_t off = (size_t)(n >> 6) * WNT + (size_t)p * WPL + (kk >> 6) * 4096 +
               (n & 63) * 64 + (kk & 63);
  *(int*)(Wtl + off) = packed;
}

// ---------------------------------------------------------------------------
// Init: pack input for ALL t, zero spike buf0 + Hm + o-state, tables.
// ---------------------------------------------------------------------------
__global__ void init_k(int8_t* __restrict__ Xin, int8_t* __restrict__ Xs,
                       float* __restrict__ Hm, const float* __restrict__ input,
                       const float* __restrict__ tau_h,
                       const float* __restrict__ tau_o,
                       float* __restrict__ AlphaH, float* __restrict__ AlphaO,
                       const float* __restrict__ w_ho, double* __restrict__ WhoD,
                       float* __restrict__ Om, float* __restrict__ Osp,
                       float* __restrict__ Osu, float* __restrict__ Mo) {
  int id = blockIdx.x * 256 + threadIdx.x;   // [0, 65536)
  {
    int b = id >> 8, i4 = (id & 255) * 4;
    for (int t = 0; t < T_; ++t) {
      float4 v = *(const float4*)(input + ((size_t)(b * T_ + t) << 10) + i4);
      uchar4 pk;
      pk.x = v.x > 0.5f ? 1 : 0;
      pk.y = v.y > 0.5f ? 1 : 0;
      pk.z = v.z > 0.5f ? 1 : 0;
      pk.w = v.w > 0.5f ? 1 : 0;
      *(uchar4*)(Xin + (size_t)t * XIN_T + (b >> 6) * 65536 + (i4 >> 6) * 4096 +
                 (b & 63) * 64 + (i4 & 63)) = pk;
    }
  }
  *(double*)(Xs + (size_t)id * 8) = 0.0;        // zero spike buf0
  *(float4*)(Hm + (size_t)id * 8) = make_float4(0.f, 0.f, 0.f, 0.f);
  *(float4*)(Hm + (size_t)id * 8 + 4) = make_float4(0.f, 0.f, 0.f, 0.f);
  if (id < 32 * O_ * 64) {                      // WhoD [nt 32][o 20][hl 64]
    int nt = id / 1280, rem = id % 1280, o = rem / 64, hl = rem & 63;
    WhoD[id] = (double)w_ho[o * H_ + nt * 64 + hl];
  }
  if (id < H_) AlphaH[id] = (float)exp((double)(-1.0f / tau_h[id]));
  if (id < O_) AlphaO[id] = (float)exp((double)(-1.0f / tau_o[id]));
  if (id < B_ * O_) {
    Om[id] = 0.f; Osp[id] = 0.f; Osu[id] = 0.f; Mo[id] = 0.f;
  }
}

// ---------------------------------------------------------------------------
// Per-step kernel: 256 blocks x 512 threads (1/CU, 8 waves = 2/SIMD).
// Block (nt, mt): 32 batch x 64 h, full K. Wave (c = col-half, k = K-quarter).
// ---------------------------------------------------------------------------
__global__ __launch_bounds__(512, 1) void step_k(
    const int8_t* __restrict__ Wtl, const int8_t* __restrict__ Xin,
    int8_t* __restrict__ Xs, float* __restrict__ Hm, double* __restrict__ Po,
    const double* __restrict__ WhoD, const float* __restrict__ AlphaH,
    const float* __restrict__ AlphaO, float* __restrict__ Om,
    float* __restrict__ Osp, float* __restrict__ Osu, float* __restrict__ Mo,
    int t) {
  __shared__ double WhoL[1280];
  __shared__ __align__(16) int8_t red[49152];   // [c 2][s 2][acc 12][lane 64]x16B
  __shared__ int8_t spk_lT[2048];               // [col 64][row 32]
  __shared__ float om_l[O_];

  const int j = blockIdx.x;
  const int nt = (j & 7) * 4 + (j >> 6);   // XCD-grouped weight panels
  const int mt = (j >> 3) & 7;
  const int tid = threadIdx.x;
  const int l = tid & 63, wv = tid >> 6;
  const int c = wv >> 2, k = wv & 3;
  const int r_ = l & 15, q = l >> 4;

  for (int i = tid; i < 1280; i += 512) WhoL[i] = WhoD[nt * 1280 + i];

  // ---- head: o-phase for step t-1 (block j = batch j) ----
  if (t > 0 && tid < O_) {
    const double* pp = Po + ((size_t)(((t - 1) & 1) * 256 + j) * 32) * 20 + tid;
    double s = 0.0;
#pragma unroll
    for (int n2 = 0; n2 < 32; ++n2) s += pp[n2 * 20];
    float r = (float)s;
    float m = Om[j * O_ + tid] * AlphaO[tid] * (1.0f - Osp[j * O_ + tid]) + r;
    om_l[tid] = m;
  }
  __syncthreads();
  if (t > 0 && tid < O_) {
    float m = om_l[tid];
    float mx = om_l[0];
#pragma unroll
    for (int o = 1; o < O_; ++o) mx = fmaxf(mx, om_l[o]);
    float se = 0.f;
#pragma unroll
    for (int o = 0; o < O_; ++o) se += expf(om_l[o] - mx);
    float sp = (m - 0.3f) > 0.f ? 1.f : 0.f;
    Om[j * O_ + tid] = m;
    Osp[j * O_ + tid] = sp;
    Osu[j * O_ + tid] += sp;
    Mo[j * O_ + tid] += expf(m - mx) / se;
  }

  // ---- K-loop: 12 slabs per wave, no barriers, depth-1 rotation ----
  const int arow = ((mt & 1) * 32 + r_) * 64 + q * 16;
  const int8_t* Ain = Xin + (size_t)t * XIN_T + (mt >> 1) * 65536 + arow;
  const int8_t* Asp = Xs + (size_t)(t & 1) * XS_BUF + (mt >> 1) * 131072 + arow;
  const int8_t* Bw = Wtl + (size_t)nt * WNT + (c * 32 + r_) * 64 + q * 16;
  const int u0 = k * 12;

  intx4 acc[2][2][3];   // [fr][fc][p]
#pragma unroll
  for (int fr = 0; fr < 2; ++fr)
#pragma unroll
    for (int fc = 0; fc < 2; ++fc)
#pragma unroll
      for (int p = 0; p < 3; ++p) acc[fr][fc][p] = (intx4){0, 0, 0, 0};

  intx4 a[2][2], b[2][2][3];
  {
    const int8_t* ap = (u0 < 16) ? (Ain + u0 * 4096) : (Asp + (u0 - 16) * 4096);
    a[0][0] = *(const intx4*)ap;
    a[0][1] = *(const intx4*)(ap + 1024);
    const int8_t* bp = Bw + u0 * 4096;
#pragma unroll
    for (int p = 0; p < 3; ++p)
#pragma unroll
      for (int fc = 0; fc < 2; ++fc)
        b[0][fc][p] = *(const intx4*)(bp + p * WPL + fc * 1024);
  }
#pragma unroll
  for (int i = 0; i < 12; ++i) {
    const int cur = i & 1, nxt = cur ^ 1;
    if (i < 11) {
      const int un = u0 + i + 1;
      const int8_t* ap = (un < 16) ? (Ain + un * 4096) : (Asp + (un - 16) * 4096);
      a[nxt][0] = *(const intx4*)ap;
      a[nxt][1] = *(const intx4*)(ap + 1024);
      const int8_t* bp = Bw + un * 4096;
#pragma unroll
      for (int p = 0; p < 3; ++p)
#pragma unroll
        for (int fc = 0; fc < 2; ++fc)
          b[nxt][fc][p] = *(const intx4*)(bp + p * WPL + fc * 1024);
    }
#pragma unroll
    for (int p = 0; p < 3; ++p)
#pragma unroll
      for (int fc = 0; fc < 2; ++fc) {
        acc[0][fc][p] = __builtin_amdgcn_mfma_i32_16x16x64_i8(
            a[cur][0], b[cur][fc][p], acc[0][fc][p], 0, 0, 0);
        acc[1][fc][p] = __builtin_amdgcn_mfma_i32_16x16x64_i8(
            a[cur][1], b[cur][fc][p], acc[1][fc][p], 0, 0, 0);
      }
  }

  // ---- exact K-quarter merge: pairwise LDS tree, 2 barriers ----
  // slot(c,s): red + ((c*2+s)*12 + accidx)*1024 + l*16
#define REDP(s, idx) (red + (((c * 2 + (s)) * 12 + (idx)) * 64 + l) * 16)
  if (k == 1 || k == 3) {
    const int s = k >> 1;
#pragma unroll
    for (int fr = 0; fr < 2; ++fr)
#pragma unroll
      for (int fc = 0; fc < 2; ++fc)
#pragma unroll
        for (int p = 0; p < 3; ++p)
          *(intx4*)REDP(s, fr * 6 + fc * 3 + p) = acc[fr][fc][p];
  }
  __syncthreads();
  if (k == 0 || k == 2) {
    const int s = k >> 1;
#pragma unroll
    for (int fr = 0; fr < 2; ++fr)
#pragma unroll
      for (int fc = 0; fc < 2; ++fc)
#pragma unroll
        for (int p = 0; p < 3; ++p)
          acc[fr][fc][p] = acc[fr][fc][p] +
                           *(const intx4*)REDP(s, fr * 6 + fc * 3 + p);
    if (k == 2) {
#pragma unroll
      for (int fr = 0; fr < 2; ++fr)
#pragma unroll
        for (int fc = 0; fc < 2; ++fc)
#pragma unroll
          for (int p = 0; p < 3; ++p)
            *(intx4*)REDP(1, fr * 6 + fc * 3 + p) = acc[fr][fc][p];
    }
  }
  __syncthreads();

  // ---- hidden epilogue (waves k==0): full-K sums, decay, spike ----
  if (k == 0) {
    int8_t* Xw = Xs + (size_t)((t + 1) & 1) * XS_BUF;
    const int h0 = nt * 64 + c * 32 + r_;
#pragma unroll
    for (int fc = 0; fc < 2; ++fc) {
      const int h = h0 + fc * 16;
      const float alpha = AlphaH[h];
#pragma unroll
      for (int fr = 0; fr < 2; ++fr) {
        intx4 s0 = acc[fr][fc][0] + *(const intx4*)REDP(1, fr * 6 + fc * 3 + 0);
        intx4 s1 = acc[fr][fc][1] + *(const intx4*)REDP(1, fr * 6 + fc * 3 + 1);
        intx4 s2 = acc[fr][fc][2] + *(const intx4*)REDP(1, fr * 6 + fc * 3 + 2);
        unsigned spkpack = 0;
#pragma unroll
        for (int jj = 0; jj < 4; ++jj) {
          ll_t Sv = (ll_t)s0[jj] + ((ll_t)s1[jj] << 8) + ((ll_t)s2[jj] << 16);
          float M = (float)((double)Sv * 7.450580596923828125e-9);  // * 2^-27
          const int brow = mt * 32 + fr * 16 + q * 4 + jj;
          const int idx = brow * H_ + h;
          float hp = Hm[idx];
          float spf = (hp - 0.3f) > 0.f ? 1.f : 0.f;
          float hm = M + hp * alpha * (1.0f - spf);   // fp32 program order
          Hm[idx] = hm;
          unsigned spk = (hm - 0.3f) > 0.f ? 1u : 0u;
          Xw[(brow >> 6) * 131072 + (h >> 6) * 4096 + (brow & 63) * 64 +
             (h & 63)] = (int8_t)spk;
          spkpack |= spk << (8 * jj);
        }
        *(unsigned*)(spk_lT + (c * 32 + fc * 16 + r_) * 32 + fr * 16 + q * 4) =
            spkpack;
      }
    }
  }
  __syncthreads();

  // ---- o-partials: 64-h double dot, Po[t&1][b][nt][o] ----
  if (tid < 128) {
    const int bl = tid >> 2, og = (tid & 3) * 5;
    const double* W0 = WhoL + og * 64;
    double a0 = 0, a1 = 0, a2 = 0, a3 = 0, a4 = 0;
#pragma unroll
    for (int hl = 0; hl < 64; ++hl) {
      double m = (double)spk_lT[hl * 32 + bl];
      a0 += m * W0[hl];
      a1 += m * W0[64 + hl];
      a2 += m * W0[128 + hl];
      a3 += m * W0[192 + hl];
      a4 += m * W0[256 + hl];
    }
    double* dst =
        Po + ((size_t)((t & 1) * 256 + mt * 32 + bl) * 32 + nt) * 20 + og;
    dst[0] = a0; dst[1] = a1; dst[2] = a2; dst[3] = a3; dst[4] = a4;
  }
#undef REDP
}

// ---------------------------------------------------------------------------
// Final o-phase (t=49) + output write. 256 blocks x 64 threads.
// ---------------------------------------------------------------------------
__global__ void final_k(const double* __restrict__ Po,
                        const float* __restrict__ AlphaO,
                        const float* __restrict__ Om,
                        const float* __restrict__ Osp,
                        const float* __restrict__ Osu,
                        const float* __restrict__ Mo, float* __restrict__ out) {
  __shared__ float om_l[O_];
  const int j = blockIdx.x, tid = threadIdx.x;
  if (tid < O_) {
    const double* pp = Po + ((size_t)(256 + j) * 32) * 20 + tid;   // slot 1
    double s = 0.0;
#pragma unroll
    for (int n2 = 0; n2 < 32; ++n2) s += pp[n2 * 20];
    float r = (float)s;
    float m = Om[j * O_ + tid] * AlphaO[tid] * (1.0f - Osp[j * O_ + tid]) + r;
    om_l[tid] = m;
  }
  __syncthreads();
  if (tid < O_) {
    float m = om_l[tid];
    float mx = om_l[0];
#pragma unroll
    for (int o = 1; o < O_; ++o) mx = fmaxf(mx, om_l[o]);
    float se = 0.f;
#pragma unroll
    for (int o = 0; o < O_; ++o) se += expf(om_l[o] - mx);
    float sp = (m - 0.3f) > 0.f ? 1.f : 0.f;
    out[j * O_ + tid] = (Osu[j * O_ + tid] + sp) / 50.0f;
    out[B_ * O_ + j * O_ + tid] = Mo[j * O_ + tid] + expf(m - mx) / se;
  }
}

// ---------------------------------------------------------------------------
extern "C" void kernel_launch(void* const* d_in, const int* in_sizes, int n_in,
                              void* d_out, int out_size, void* d_ws, size_t ws_size,
                              hipStream_t stream) {
  const float* input = (const float*)d_in[0];
  const float* w_ih  = (const float*)d_in[1];
  const float* w_hh  = (const float*)d_in[2];
  const float* w_ho  = (const float*)d_in[3];
  const float* tau_h = (const float*)d_in[4];
  const float* tau_o = (const float*)d_in[5];

  char* ws = (char*)d_ws;
  int8_t* Wtl    = (int8_t*)(ws);
  int8_t* Xin    = (int8_t*)(ws + 18874368);
  int8_t* Xs     = (int8_t*)(ws + 31981568);
  double* Po     = (double*)(ws + 33030144);
  float*  Hm     = (float*)(ws + 35651584);
  double* WhoD   = (double*)(ws + 37748736);
  float*  AlphaH = (float*)(ws + 38076416);
  float*  AlphaO = (float*)(ws + 38084608);
  float*  Om     = (float*)(ws + 38084736);
  float*  Osp    = (float*)(ws + 38105216);
  float*  Osu    = (float*)(ws + 38125696);
  float*  Mo     = (float*)(ws + 38146176);
  float*  out    = (float*)d_out;

  prep_w<<<2048 * 9, 256, 0, stream>>>(w_ih, w_hh, Wtl);
  init_k<<<256, 256, 0, stream>>>(Xin, Xs, Hm, input, tau_h, tau_o, AlphaH,
                                  AlphaO, w_ho, WhoD, Om, Osp, Osu, Mo);
  for (int t = 0; t < T_; ++t) {
    step_k<<<256, 512, 0, stream>>>(Wtl, Xin, Xs, Hm, Po, WhoD, AlphaH, AlphaO,
                                    Om, Osp, Osu, Mo, t);
  }
  final_k<<<256, 64, 0, stream>>>(Po, AlphaO, Om, Osp, Osu, Mo, out);
}

// Round 10
// 1108.034 us; speedup vs baseline: 3.1304x; 1.0017x over previous
//
#include <hip/hip_runtime.h>
#include <stdint.h>
#include <math.h>

// ---------------------------------------------------------------------------
// RSNN forward, MI355X. EXACT integer hidden GEMM (rounds 3-9, absmax
// 0.0156): 27-bit fixed-point weights -> 3 signed base-256 i8 digit planes,
// binary activations, i32 MFMA, exact int64 recombination, single fp32
// round, fp32 program-order decay.
// Round-10: more TLP. 512 blocks x 512 threads = 2 blocks/CU, 16 waves/CU
// (4/SIMD, forced via __launch_bounds__(512,4)). Block = 32 batch x 32 h,
// full K; all 8 waves compute the same 32x32 tile over K-eighths (6 slabs,
// 12 MFMAs each); exact pairwise i32 LDS tree (3 barriers) merges them.
// h-split keeps per-CU weight port traffic unchanged (576 KB) while
// doubling in-flight loads. XCD swizzle: 8 same-nt blocks share blockIdx%8.
// ---------------------------------------------------------------------------

#define B_   256
#define T_   50
#define I_   1024
#define H_   2048
#define O_   20
#define XIN_T  262144    // input bytes per t: 4 bt * 16 kx * 4096
#define XS_BUF 524288    // one spike buffer: 4 bt * 32 kx * 4096
#define WNT 294912       // weight bytes per nt (32 cols): 3 * 48 * 2048
#define WPL 98304        // bytes per plane within an nt

typedef __attribute__((ext_vector_type(4))) int intx4;
typedef long long ll_t;

// ---------------------------------------------------------------------------
// Weight prep: digit p of W(n,kk) -> [nt 64][p 3][kx 48][row 32][64B]
// ---------------------------------------------------------------------------
__device__ __forceinline__ int digit_of(float v, int p) {
  int W = (int)rintf(v * 134217728.0f);   // exact: |W| <= 2^22
  int c0 = ((W + 128) & 255) - 128;
  int W1 = (W - c0) >> 8;
  int c1 = ((W1 + 128) & 255) - 128;
  int W2 = (W1 - c1) >> 8;
  return (p == 0) ? c0 : (p == 1) ? c1 : W2;
}

__global__ void prep_w(const float* __restrict__ w_ih,
                       const float* __restrict__ w_hh,
                       int8_t* __restrict__ Wtl) {
  int blk = blockIdx.x;
  int n = blk / 9, kg = blk % 9;
  int k9 = (kg * 256 + (int)threadIdx.x) * 4;   // [0, 9216)
  int p = k9 / 3072, kk = k9 % 3072;
  const float* src = (kk < 1024) ? (w_ih + n * I_ + kk)
                                 : (w_hh + n * H_ + (kk - 1024));
  float4 v = *(const float4*)src;
  int d0 = digit_of(v.x, p) & 255;
  int d1 = digit_of(v.y, p) & 255;
  int d2 = digit_of(v.z, p) & 255;
  int d3 = digit_of(v.w, p) & 255;
  int packed = d0 | (d1 << 8) | (d2 << 16) | (d3 << 24);
  size_t off = (size_t)(n >> 5) * WNT + (size_t)p * WPL + (kk >> 6) * 2048 +
               (n & 31) * 64 + (kk & 63);
  *(int*)(Wtl + off) = packed;
}

// ---------------------------------------------------------------------------
// Init: pack input for ALL t, zero spike buf0 + Hm + o-state, tables.
// ---------------------------------------------------------------------------
__global__ void init_k(int8_t* __restrict__ Xin, int8_t* __restrict__ Xs,
                       float* __restrict__ Hm, const float* __restrict__ input,
                       const float* __restrict__ tau_h,
                       const float* __restrict__ tau_o,
                       float* __restrict__ AlphaH, float* __restrict__ AlphaO,
                       const float* __restrict__ w_ho, double* __restrict__ WhoD,
                       float* __restrict__ Om, float* __restrict__ Osp,
                       float* __restrict__ Osu, float* __restrict__ Mo) {
  int id = blockIdx.x * 256 + threadIdx.x;   // [0, 65536)
  {
    int b = id >> 8, i4 = (id & 255) * 4;
    for (int t = 0; t < T_; ++t) {
      float4 v = *(const float4*)(input + ((size_t)(b * T_ + t) << 10) + i4);
      uchar4 pk;
      pk.x = v.x > 0.5f ? 1 : 0;
      pk.y = v.y > 0.5f ? 1 : 0;
      pk.z = v.z > 0.5f ? 1 : 0;
      pk.w = v.w > 0.5f ? 1 : 0;
      *(uchar4*)(Xin + (size_t)t * XIN_T + (b >> 6) * 65536 + (i4 >> 6) * 4096 +
                 (b & 63) * 64 + (i4 & 63)) = pk;
    }
  }
  *(double*)(Xs + (size_t)id * 8) = 0.0;        // zero spike buf0
  *(float4*)(Hm + (size_t)id * 8) = make_float4(0.f, 0.f, 0.f, 0.f);
  *(float4*)(Hm + (size_t)id * 8 + 4) = make_float4(0.f, 0.f, 0.f, 0.f);
  if (id < 64 * O_ * 32) {                      // WhoD [nt 64][o 20][hl 32]
    int nt = id / 640, rem = id % 640, o = rem / 32, hl = rem & 31;
    WhoD[id] = (double)w_ho[o * H_ + nt * 32 + hl];
  }
  if (id < H_) AlphaH[id] = (float)exp((double)(-1.0f / tau_h[id]));
  if (id < O_) AlphaO[id] = (float)exp((double)(-1.0f / tau_o[id]));
  if (id < B_ * O_) {
    Om[id] = 0.f; Osp[id] = 0.f; Osu[id] = 0.f; Mo[id] = 0.f;
  }
}

// ---------------------------------------------------------------------------
// Per-step kernel: 512 blocks x 512 threads (2/CU, 4 waves/SIMD).
// Block (nt in [0,64), mt in [0,8)): 32 batch x 32 h, full K.
// Wave k in [0,8) = K-eighth (6 slabs).
// ---------------------------------------------------------------------------
__global__ __launch_bounds__(512, 4) void step_k(
    const int8_t* __restrict__ Wtl, const int8_t* __restrict__ Xin,
    int8_t* __restrict__ Xs, float* __restrict__ Hm, double* __restrict__ Po,
    const double* __restrict__ WhoD, const float* __restrict__ AlphaH,
    const float* __restrict__ AlphaO, float* __restrict__ Om,
    float* __restrict__ Osp, float* __restrict__ Osu, float* __restrict__ Mo,
    int t) {
  __shared__ double WhoL[640];
  __shared__ __align__(16) int8_t red[49152];   // 4 slots x 12 accs x 64 x 16B
  __shared__ int8_t spk_lT[1024];               // [col 32][row 32]
  __shared__ float om_l[O_];

  const int j = blockIdx.x;
  const int nt = (j & 7) * 8 + ((j >> 3) & 7);  // same nt -> same j%8 (XCD)
  const int mt = j >> 6;
  const int tid = threadIdx.x;
  const int l = tid & 63, k = tid >> 6;
  const int r_ = l & 15, q = l >> 4;

  for (int i = tid; i < 640; i += 512) WhoL[i] = WhoD[nt * 640 + i];

  // ---- head: o-phase for step t-1 (blocks j<256, batch j) ----
  if (t > 0 && j < B_ && tid < O_) {
    const double* pp = Po + ((size_t)(((t - 1) & 1) * 256 + j) * 64) * 20 + tid;
    double s = 0.0;
#pragma unroll
    for (int n2 = 0; n2 < 64; ++n2) s += pp[n2 * 20];
    float r = (float)s;
    float m = Om[j * O_ + tid] * AlphaO[tid] * (1.0f - Osp[j * O_ + tid]) + r;
    om_l[tid] = m;
  }
  __syncthreads();
  if (t > 0 && j < B_ && tid < O_) {
    float m = om_l[tid];
    float mx = om_l[0];
#pragma unroll
    for (int o = 1; o < O_; ++o) mx = fmaxf(mx, om_l[o]);
    float se = 0.f;
#pragma unroll
    for (int o = 0; o < O_; ++o) se += expf(om_l[o] - mx);
    float sp = (m - 0.3f) > 0.f ? 1.f : 0.f;
    Om[j * O_ + tid] = m;
    Osp[j * O_ + tid] = sp;
    Osu[j * O_ + tid] += sp;
    Mo[j * O_ + tid] += expf(m - mx) / se;
  }

  // ---- K-loop: 6 slabs per wave, no barriers, depth-1 rotation ----
  const int arow = ((mt & 1) * 32 + r_) * 64 + q * 16;
  const int8_t* Ain = Xin + (size_t)t * XIN_T + (mt >> 1) * 65536 + arow;
  const int8_t* Asp = Xs + (size_t)(t & 1) * XS_BUF + (mt >> 1) * 131072 + arow;
  const int8_t* Bw = Wtl + (size_t)nt * WNT + r_ * 64 + q * 16;
  const int u0 = k * 6;

  intx4 acc[2][2][3];   // [fr][fc][p]
#pragma unroll
  for (int fr = 0; fr < 2; ++fr)
#pragma unroll
    for (int fc = 0; fc < 2; ++fc)
#pragma unroll
      for (int p = 0; p < 3; ++p) acc[fr][fc][p] = (intx4){0, 0, 0, 0};

  intx4 a[2][2], b[2][2][3];
  {
    const int8_t* ap = (u0 < 16) ? (Ain + u0 * 4096) : (Asp + (u0 - 16) * 4096);
    a[0][0] = *(const intx4*)ap;
    a[0][1] = *(const intx4*)(ap + 1024);
    const int8_t* bp = Bw + u0 * 2048;
#pragma unroll
    for (int p = 0; p < 3; ++p)
#pragma unroll
      for (int fc = 0; fc < 2; ++fc)
        b[0][fc][p] = *(const intx4*)(bp + p * WPL + fc * 1024);
  }
#pragma unroll
  for (int i = 0; i < 6; ++i) {
    const int cur = i & 1, nxt = cur ^ 1;
    if (i < 5) {
      const int un = u0 + i + 1;
      const int8_t* ap = (un < 16) ? (Ain + un * 4096) : (Asp + (un - 16) * 4096);
      a[nxt][0] = *(const intx4*)ap;
      a[nxt][1] = *(const intx4*)(ap + 1024);
      const int8_t* bp = Bw + un * 2048;
#pragma unroll
      for (int p = 0; p < 3; ++p)
#pragma unroll
        for (int fc = 0; fc < 2; ++fc)
          b[nxt][fc][p] = *(const intx4*)(bp + p * WPL + fc * 1024);
    }
#pragma unroll
    for (int p = 0; p < 3; ++p)
#pragma unroll
      for (int fc = 0; fc < 2; ++fc) {
        acc[0][fc][p] = __builtin_amdgcn_mfma_i32_16x16x64_i8(
            a[cur][0], b[cur][fc][p], acc[0][fc][p], 0, 0, 0);
        acc[1][fc][p] = __builtin_amdgcn_mfma_i32_16x16x64_i8(
            a[cur][1], b[cur][fc][p], acc[1][fc][p], 0, 0, 0);
      }
  }

  // ---- exact K-eighth merge: pairwise i32 LDS tree, 3 barriers ----
#define REDP(slot, idx) (red + (((slot) * 12 + (idx)) * 64 + l) * 16)
#define ACCIDX(fr, fc, p) ((fr) * 6 + (fc) * 3 + (p))
  if (k & 1) {
#pragma unroll
    for (int fr = 0; fr < 2; ++fr)
#pragma unroll
      for (int fc = 0; fc < 2; ++fc)
#pragma unroll
        for (int p = 0; p < 3; ++p)
          *(intx4*)REDP(k >> 1, ACCIDX(fr, fc, p)) = acc[fr][fc][p];
  }
  __syncthreads();
  if (!(k & 1)) {
#pragma unroll
    for (int fr = 0; fr < 2; ++fr)
#pragma unroll
      for (int fc = 0; fc < 2; ++fc)
#pragma unroll
        for (int p = 0; p < 3; ++p)
          acc[fr][fc][p] =
              acc[fr][fc][p] + *(const intx4*)REDP(k >> 1, ACCIDX(fr, fc, p));
  }
  __syncthreads();
  if (k == 2 || k == 6) {
#pragma unroll
    for (int fr = 0; fr < 2; ++fr)
#pragma unroll
      for (int fc = 0; fc < 2; ++fc)
#pragma unroll
        for (int p = 0; p < 3; ++p)
          *(intx4*)REDP(k >> 2, ACCIDX(fr, fc, p)) = acc[fr][fc][p];
  }
  __syncthreads();
  if (k == 0 || k == 4) {
#pragma unroll
    for (int fr = 0; fr < 2; ++fr)
#pragma unroll
      for (int fc = 0; fc < 2; ++fc)
#pragma unroll
        for (int p = 0; p < 3; ++p)
          acc[fr][fc][p] =
              acc[fr][fc][p] + *(const intx4*)REDP(k >> 2, ACCIDX(fr, fc, p));
  }
  __syncthreads();
  if (k == 4) {
#pragma unroll
    for (int fr = 0; fr < 2; ++fr)
#pragma unroll
      for (int fc = 0; fc < 2; ++fc)
#pragma unroll
        for (int p = 0; p < 3; ++p)
          *(intx4*)REDP(0, ACCIDX(fr, fc, p)) = acc[fr][fc][p];
  }
  __syncthreads();

  // ---- hidden epilogue (wave k==0): full-K sums, decay, spike ----
  if (k == 0) {
    int8_t* Xw = Xs + (size_t)((t + 1) & 1) * XS_BUF;
#pragma unroll
    for (int fc = 0; fc < 2; ++fc) {
      const int h = nt * 32 + fc * 16 + r_;
      const float alpha = AlphaH[h];
#pragma unroll
      for (int fr = 0; fr < 2; ++fr) {
        intx4 s0 = acc[fr][fc][0] + *(const intx4*)REDP(0, ACCIDX(fr, fc, 0));
        intx4 s1 = acc[fr][fc][1] + *(const intx4*)REDP(0, ACCIDX(fr, fc, 1));
        intx4 s2 = acc[fr][fc][2] + *(const intx4*)REDP(0, ACCIDX(fr, fc, 2));
        unsigned spkpack = 0;
#pragma unroll
        for (int jj = 0; jj < 4; ++jj) {
          ll_t Sv = (ll_t)s0[jj] + ((ll_t)s1[jj] << 8) + ((ll_t)s2[jj] << 16);
          float M = (float)((double)Sv * 7.450580596923828125e-9);  // * 2^-27
          const int brow = mt * 32 + fr * 16 + q * 4 + jj;
          const int idx = brow * H_ + h;
          float hp = Hm[idx];
          float spf = (hp - 0.3f) > 0.f ? 1.f : 0.f;
          float hm = M + hp * alpha * (1.0f - spf);   // fp32 program order
          Hm[idx] = hm;
          unsigned spk = (hm - 0.3f) > 0.f ? 1u : 0u;
          Xw[(brow >> 6) * 131072 + (h >> 6) * 4096 + (brow & 63) * 64 +
             (h & 63)] = (int8_t)spk;
          spkpack |= spk << (8 * jj);
        }
        *(unsigned*)(spk_lT + (fc * 16 + r_) * 32 + fr * 16 + q * 4) = spkpack;
      }
    }
  }
  __syncthreads();

  // ---- o-partials: 32-h double dot, Po[t&1][b][nt][o] ----
  if (tid < 128) {
    const int bl = tid >> 2, og = (tid & 3) * 5;
    const double* W0 = WhoL + og * 32;
    double a0 = 0, a1 = 0, a2 = 0, a3 = 0, a4 = 0;
#pragma unroll
    for (int hl = 0; hl < 32; ++hl) {
      double m = (double)spk_lT[hl * 32 + bl];
      a0 += m * W0[hl];
      a1 += m * W0[32 + hl];
      a2 += m * W0[64 + hl];
      a3 += m * W0[96 + hl];
      a4 += m * W0[128 + hl];
    }
    double* dst =
        Po + ((size_t)((t & 1) * 256 + mt * 32 + bl) * 64 + nt) * 20 + og;
    dst[0] = a0; dst[1] = a1; dst[2] = a2; dst[3] = a3; dst[4] = a4;
  }
#undef REDP
#undef ACCIDX
}

// ---------------------------------------------------------------------------
// Final o-phase (t=49) + output write. 256 blocks x 64 threads.
// ---------------------------------------------------------------------------
__global__ void final_k(const double* __restrict__ Po,
                        const float* __restrict__ AlphaO,
                        const float* __restrict__ Om,
                        const float* __restrict__ Osp,
                        const float* __restrict__ Osu,
                        const float* __restrict__ Mo, float* __restrict__ out) {
  __shared__ float om_l[O_];
  const int j = blockIdx.x, tid = threadIdx.x;
  if (tid < O_) {
    const double* pp = Po + ((size_t)(256 + j) * 64) * 20 + tid;   // slot 1
    double s = 0.0;
#pragma unroll
    for (int n2 = 0; n2 < 64; ++n2) s += pp[n2 * 20];
    float r = (float)s;
    float m = Om[j * O_ + tid] * AlphaO[tid] * (1.0f - Osp[j * O_ + tid]) + r;
    om_l[tid] = m;
  }
  __syncthreads();
  if (tid < O_) {
    float m = om_l[tid];
    float mx = om_l[0];
#pragma unroll
    for (int o = 1; o < O_; ++o) mx = fmaxf(mx, om_l[o]);
    float se = 0.f;
#pragma unroll
    for (int o = 0; o < O_; ++o) se += expf(om_l[o] - mx);
    float sp = (m - 0.3f) > 0.f ? 1.f : 0.f;
    out[j * O_ + tid] = (Osu[j * O_ + tid] + sp) / 50.0f;
    out[B_ * O_ + j * O_ + tid] = Mo[j * O_ + tid] + expf(m - mx) / se;
  }
}

// ---------------------------------------------------------------------------
extern "C" void kernel_launch(void* const* d_in, const int* in_sizes, int n_in,
                              void* d_out, int out_size, void* d_ws, size_t ws_size,
                              hipStream_t stream) {
  const float* input = (const float*)d_in[0];
  const float* w_ih  = (const float*)d_in[1];
  const float* w_hh  = (const float*)d_in[2];
  const float* w_ho  = (const float*)d_in[3];
  const float* tau_h = (const float*)d_in[4];
  const float* tau_o = (const float*)d_in[5];

  char* ws = (char*)d_ws;
  // layout (bytes):
  // Wtl    @ 0          18,874,368
  // Xin    @ 18874368   13,107,200
  // Xs     @ 31981568    1,048,576
  // Po     @ 33030144    5,242,880   (2 x 256 x 64 x 20 doubles)
  // Hm     @ 38273024    2,097,152
  // WhoD   @ 40370176      327,680
  // AlphaH @ 40697856        8,192
  // AlphaO @ 40706048          128
  // Om     @ 40706176       20,480  (then Osp, Osu, Mo)
  int8_t* Wtl    = (int8_t*)(ws);
  int8_t* Xin    = (int8_t*)(ws + 18874368);
  int8_t* Xs     = (int8_t*)(ws + 31981568);
  double* Po     = (double*)(ws + 33030144);
  float*  Hm     = (float*)(ws + 38273024);
  double* WhoD   = (double*)(ws + 40370176);
  float*  AlphaH = (float*)(ws + 40697856);
  float*  AlphaO = (float*)(ws + 40706048);
  float*  Om     = (float*)(ws + 40706176);
  float*  Osp    = (float*)(ws + 40726656);
  float*  Osu    = (float*)(ws + 40747136);
  float*  Mo     = (float*)(ws + 40767616);
  float*  out    = (float*)d_out;

  prep_w<<<2048 * 9, 256, 0, stream>>>(w_ih, w_hh, Wtl);
  init_k<<<256, 256, 0, stream>>>(Xin, Xs, Hm, input, tau_h, tau_o, AlphaH,
                                  AlphaO, w_ho, WhoD, Om, Osp, Osu, Mo);
  for (int t = 0; t < T_; ++t) {
    step_k<<<512, 512, 0, stream>>>(Wtl, Xin, Xs, Hm, Po, WhoD, AlphaH, AlphaO,
                                    Om, Osp, Osu, Mo, t);
  }
  final_k<<<256, 64, 0, stream>>>(Po, AlphaO, Om, Osp, Osu, Mo, out);
}